// Round 10
// baseline (52.222 us; speedup 1.0000x reference)
//
#include <hip/hip_runtime.h>
#include <hip/hip_bf16.h>

// ANI-1 per-species MLP, v10: L0 = barrier-free direct HBM streaming.
// v5/v8/v9 all plateaued ~43us with different stagings of the same
// stage->barrier->compute L0; the invariant (lockstep barrier phases +
// HBM->reg->cvt->LDS->reg round trip) was the cost. Here L0 waves are
// 4 M-grp x 2 N-grp (32 mols x 80 outs); the MFMA A-fragment is 8
// contiguous fp32 per lane straight from aev (two dwordx4, 128B/row
// coalesced), converted in-reg via paired __float2bfloat16 (compiler
// emits v_cvt_pk_bf16_f32). No X LDS buffer, no L0 barriers.
// L1-L3 unchanged from v9 (L2-resident, cheap). LDS 76 KB -> 2 blocks/CU.

typedef float f32x4 __attribute__((ext_vector_type(4)));
typedef short s16x8 __attribute__((ext_vector_type(8)));

#define NMOL   128
#define NATOM  512
#define AEV    384
#define Y0LD   168
#define Y1LD   136
#define Y2LD   104

// Wp element offsets (bf16 units)
#define PL0    61440            // 160*384
#define PL1    20480            // 128*160
#define PL2    12288            // 96*128
#define BASE0  0
#define BASE1  245760           // 4*PL0
#define BASE2  327680           // BASE1 + 4*PL1
#define WP_BYTE_OFF 262144      // partial buffer (512*128*4) first in d_ws

__device__ __forceinline__ ushort f2bf(float f) {   // RTN-even (bit trick)
    uint u = __float_as_uint(f);
    return (ushort)((u + 0x7fffu + ((u >> 16) & 1u)) >> 16);
}
__device__ __forceinline__ float bf2f(ushort h) {
    return __uint_as_float(((uint)h) << 16);
}
__device__ __forceinline__ float celu_f(float v) {
    return fmaxf(v, 0.0f) + fminf(0.1f * (__expf(10.0f * v) - 1.0f), 0.0f);
}
// paired hw convert: compiler fuses into v_cvt_pk_bf16_f32 (don't hand-write asm)
__device__ __forceinline__ uint pk2bf(float x, float y) {
    __hip_bfloat162 h2;
    h2.x = __float2bfloat16(x);
    h2.y = __float2bfloat16(y);
    return *(uint*)&h2;
}

// ---- prep: W0..W2 fp32 -> bf16 in MFMA-B-fragment order, 8 elems/thread ----
__global__ __launch_bounds__(256) void prep_kernel(
    const float* __restrict__ W0, const float* __restrict__ W1,
    const float* __restrict__ W2, ushort* __restrict__ Wp)
{
    const int idx = blockIdx.x * 256 + threadIdx.x;   // grid = 47104 (x8 elems)
    int n, k0, KS;
    size_t base;
    const float* src;
    if (idx < 30720) {                        // L0: [4][160][384], 7680 vec/species
        const int s = idx / 7680, r = idx % 7680;
        n = r / 48; k0 = (r % 48) * 8; KS = 12;
        src = W0 + (size_t)idx * 8;
        base = BASE0 + (size_t)s * PL0;
    } else if (idx < 40960) {                 // L1: [4][128][160], 2560 vec/species
        const int i2 = idx - 30720;
        const int s = i2 / 2560, r = i2 % 2560;
        n = r / 20; k0 = (r % 20) * 8; KS = 5;
        src = W1 + (size_t)i2 * 8;
        base = BASE1 + (size_t)s * PL1;
    } else {                                  // L2: [4][96][128], 1536 vec/species
        const int i2 = idx - 40960;
        const int s = i2 / 1536, r = i2 % 1536;
        n = r / 16; k0 = (r % 16) * 8; KS = 4;
        src = W2 + (size_t)i2 * 8;
        base = BASE2 + (size_t)s * PL2;
    }
    const float4 v0 = *(const float4*)(src);
    const float4 v1 = *(const float4*)(src + 4);
    const size_t fo = (size_t)((((n >> 4) * KS + (k0 >> 5)) * 64
                                + ((k0 & 31) >> 3) * 16 + (n & 15)) * 8);
    uint4 w;
    w.x = (uint)f2bf(v0.x) | ((uint)f2bf(v0.y) << 16);
    w.y = (uint)f2bf(v0.z) | ((uint)f2bf(v0.w) << 16);
    w.z = (uint)f2bf(v1.x) | ((uint)f2bf(v1.y) << 16);
    w.w = (uint)f2bf(v1.z) | ((uint)f2bf(v1.w) << 16);
    *(uint4*)(Wp + base + fo) = w;
}

__global__ __attribute__((amdgpu_flat_work_group_size(512, 512),
                          amdgpu_waves_per_eu(4, 4)))
void ani_mfma_kernel(
    const float* __restrict__ aev, const int* __restrict__ species,
    const ushort* __restrict__ Wp,
    const float* __restrict__ b0, const float* __restrict__ b1,
    const float* __restrict__ b2,
    const float* __restrict__ W3, const float* __restrict__ b3,
    float* __restrict__ partial)
{
    __shared__ __align__(16) ushort y0buf[NMOL * Y0LD];   // 43008 B: Y0 -> Y2
    __shared__ __align__(16) ushort y1buf[NMOL * Y1LD];   // 34816 B: Y1 -> red

    const int a    = blockIdx.x;        // atom
    const int tid  = threadIdx.x;
    const int lane = tid & 63;
    const int wid  = tid >> 6;

    const int s = species[a];
    const ushort* Bh0 = Wp + BASE0 + (size_t)s * PL0;
    const ushort* Bh1 = Wp + BASE1 + (size_t)s * PL1;
    const ushort* Bh2 = Wp + BASE2 + (size_t)s * PL2;
    const float* b0s = b0 + s * 160;
    const float* b1s = b1 + s * 128;
    const float* b2s = b2 + s * 96;
    const float* w3s = W3 + s * 96;
    const float  bb3 = b3[s];

    const f32x4 zero = {0.f, 0.f, 0.f, 0.f};

    // ================= L0: 384 -> 160, barrier-free direct streaming =======
    // wave layout: mgrp0 = wid>>1 (0..3, 32 mols), ngrp0 = wid&1 (0..1, 80 outs)
    {
        const int mgrp0 = wid >> 1;
        const int ngrp0 = wid & 1;
        // lane l: mol = mgrp0*32 + mf*16 + (l&15); k = gks*32 + (l>>4)*8 + j
        const float* arow = aev + ((size_t)(mgrp0 * 32 + (lane & 15)) * NATOM + a) * AEV
                            + (lane >> 4) * 8;
        const size_t AMF = (size_t)16 * NATOM * AEV;   // +16 molecules

        f32x4 acc0[2][5];
        #pragma unroll
        for (int mf = 0; mf < 2; ++mf)
            #pragma unroll
            for (int nf = 0; nf < 5; ++nf) acc0[mf][nf] = zero;

        #pragma unroll
        for (int gks = 0; gks < 12; ++gks) {
            s16x8 ah[2];
            #pragma unroll
            for (int mf = 0; mf < 2; ++mf) {
                const float* ap = arow + mf * AMF + gks * 32;
                const float4 lo = *(const float4*)(ap);
                const float4 hi = *(const float4*)(ap + 4);
                union { s16x8 v; uint u[4]; } r;
                r.u[0] = pk2bf(lo.x, lo.y);
                r.u[1] = pk2bf(lo.z, lo.w);
                r.u[2] = pk2bf(hi.x, hi.y);
                r.u[3] = pk2bf(hi.z, hi.w);
                ah[mf] = r.v;
            }
            #pragma unroll
            for (int nf = 0; nf < 5; ++nf) {
                const s16x8 bh = *(const s16x8*)(
                    Bh0 + ((size_t)((ngrp0 * 5 + nf) * 12 + gks) * 64 + lane) * 8);
                acc0[0][nf] = __builtin_amdgcn_mfma_f32_16x16x32_bf16(ah[0], bh, acc0[0][nf], 0, 0, 0);
                acc0[1][nf] = __builtin_amdgcn_mfma_f32_16x16x32_bf16(ah[1], bh, acc0[1][nf], 0, 0, 0);
            }
        }

        // ---- L0 epilogue -> Y0 (y0buf, ld 168) ----
        #pragma unroll
        for (int nf = 0; nf < 5; ++nf) {
            const int n = (ngrp0 * 5 + nf) * 16 + (lane & 15);
            const float bv = b0s[n];
            #pragma unroll
            for (int mf = 0; mf < 2; ++mf) {
                #pragma unroll
                for (int r = 0; r < 4; ++r) {
                    const int row = mgrp0 * 32 + mf * 16 + (lane >> 4) * 4 + r;
                    y0buf[row * Y0LD + n] = f2bf(celu_f(acc0[mf][nf][r] + bv));
                }
            }
        }
    }

    // L1 B preload (flies during the barrier)
    const int mgrp = wid >> 2;          // 0..1 (64-row groups) for L1..L3
    const int ngrp = wid & 3;           // 0..3
    const bool has3 = (ngrp < 2);
    s16x8 b1r[2][5];
    #pragma unroll
    for (int ks = 0; ks < 5; ++ks) {
        b1r[0][ks] = *(const s16x8*)(Bh1 + ((size_t)((ngrp    ) * 5 + ks) * 64 + lane) * 8);
        b1r[1][ks] = *(const s16x8*)(Bh1 + ((size_t)((ngrp + 4) * 5 + ks) * 64 + lane) * 8);
    }
    __syncthreads();

    // ---- L1: 160 -> 128 (A from Y0/y0buf, C -> Y1/y1buf) ----
    f32x4 acc1[4][2];
    #pragma unroll
    for (int mf = 0; mf < 4; ++mf) { acc1[mf][0] = zero; acc1[mf][1] = zero; }
    #pragma unroll
    for (int ks = 0; ks < 5; ++ks) {
        s16x8 ah[4];
        #pragma unroll
        for (int mf = 0; mf < 4; ++mf)
            ah[mf] = *(const s16x8*)(y0buf + (mgrp * 64 + mf * 16 + (lane & 15)) * Y0LD
                                     + ks * 32 + (lane >> 4) * 8);
        #pragma unroll
        for (int mf = 0; mf < 4; ++mf) {
            acc1[mf][0] = __builtin_amdgcn_mfma_f32_16x16x32_bf16(ah[mf], b1r[0][ks], acc1[mf][0], 0, 0, 0);
            acc1[mf][1] = __builtin_amdgcn_mfma_f32_16x16x32_bf16(ah[mf], b1r[1][ks], acc1[mf][1], 0, 0, 0);
        }
    }

    // L2 B preload (completes by the post-L1-epilogue barrier)
    s16x8 b2r[2][4];
    #pragma unroll
    for (int ks = 0; ks < 4; ++ks)
        b2r[0][ks] = *(const s16x8*)(Bh2 + ((size_t)((ngrp) * 4 + ks) * 64 + lane) * 8);
    if (has3) {
        #pragma unroll
        for (int ks = 0; ks < 4; ++ks)
            b2r[1][ks] = *(const s16x8*)(Bh2 + ((size_t)((ngrp + 4) * 4 + ks) * 64 + lane) * 8);
    }

    // ---- L1 epilogue -> Y1 (y1buf, ld 136) ----
    #pragma unroll
    for (int t = 0; t < 2; ++t) {
        const int n = (ngrp + 4 * t) * 16 + (lane & 15);
        const float bv = b1s[n];
        #pragma unroll
        for (int mf = 0; mf < 4; ++mf) {
            #pragma unroll
            for (int r = 0; r < 4; ++r) {
                const int row = mgrp * 64 + mf * 16 + (lane >> 4) * 4 + r;
                y1buf[row * Y1LD + n] = f2bf(celu_f(acc1[mf][t][r] + bv));
            }
        }
    }
    __syncthreads();

    // ---- L2: 128 -> 96 (A from Y1/y1buf, C -> Y2/y0buf ld 104) ----
    f32x4 acc2[4][2];
    #pragma unroll
    for (int mf = 0; mf < 4; ++mf) { acc2[mf][0] = zero; acc2[mf][1] = zero; }
    #pragma unroll
    for (int ks = 0; ks < 4; ++ks) {
        s16x8 ah[4];
        #pragma unroll
        for (int mf = 0; mf < 4; ++mf)
            ah[mf] = *(const s16x8*)(y1buf + (mgrp * 64 + mf * 16 + (lane & 15)) * Y1LD
                                     + ks * 32 + (lane >> 4) * 8);
        #pragma unroll
        for (int mf = 0; mf < 4; ++mf) {
            acc2[mf][0] = __builtin_amdgcn_mfma_f32_16x16x32_bf16(ah[mf], b2r[0][ks], acc2[mf][0], 0, 0, 0);
            if (has3)
                acc2[mf][1] = __builtin_amdgcn_mfma_f32_16x16x32_bf16(ah[mf], b2r[1][ks], acc2[mf][1], 0, 0, 0);
        }
    }
    __syncthreads();   // y1buf (Y1) reads done; y1buf reused for red below

    // ---- L2 epilogue -> Y2 (y0buf, ld 104) ----
    #pragma unroll
    for (int t = 0; t < 2; ++t) {
        if (t == 0 || has3) {
            const int n = (ngrp + 4 * t) * 16 + (lane & 15);   // < 96
            const float bv = b2s[n];
            #pragma unroll
            for (int mf = 0; mf < 4; ++mf) {
                #pragma unroll
                for (int r = 0; r < 4; ++r) {
                    const int row = mgrp * 64 + mf * 16 + (lane >> 4) * 4 + r;
                    y0buf[row * Y2LD + n] = f2bf(celu_f(acc2[mf][t][r] + bv));
                }
            }
        }
    }
    __syncthreads();

    // ---- L3: 96 -> 1 (fp32 vector; red in y1buf) ----
    {
        float* red = (float*)y1buf;
        const int m = tid & (NMOL - 1);
        const int q = tid >> 7;       // 0..3, 24 inputs each
        float accv = 0.f;
        #pragma unroll
        for (int ii = 0; ii < 24; ++ii) {
            const int i = q * 24 + ii;
            accv = fmaf(w3s[i], bf2f(y0buf[m * Y2LD + i]), accv);
        }
        red[q * NMOL + m] = accv;
        __syncthreads();
        if (tid < NMOL) {
            const float sm = red[tid] + red[NMOL + tid] + red[2 * NMOL + tid]
                           + red[3 * NMOL + tid] + bb3;
            partial[(size_t)a * NMOL + tid] = sm;
        }
    }
}

__global__ __launch_bounds__(256) void reduce_kernel(
    const float* __restrict__ partial, float* __restrict__ out)
{
    __shared__ float red[256];
    const int m = blockIdx.x;       // molecule
    const int t = threadIdx.x;
    float sv = partial[(size_t)t * NMOL + m] + partial[(size_t)(t + 256) * NMOL + m];
    red[t] = sv;
    __syncthreads();
    #pragma unroll
    for (int w = 128; w > 0; w >>= 1) {
        if (t < w) red[t] += red[t + w];
        __syncthreads();
    }
    if (t == 0) out[m] = red[0];
}

extern "C" void kernel_launch(void* const* d_in, const int* in_sizes, int n_in,
                              void* d_out, int out_size, void* d_ws, size_t ws_size,
                              hipStream_t stream) {
    const float* aev     = (const float*)d_in[0];
    const int*   species = (const int*)  d_in[1];
    const float* W0 = (const float*)d_in[2];
    const float* b0 = (const float*)d_in[3];
    const float* W1 = (const float*)d_in[4];
    const float* b1 = (const float*)d_in[5];
    const float* W2 = (const float*)d_in[6];
    const float* b2 = (const float*)d_in[7];
    const float* W3 = (const float*)d_in[8];
    const float* b3 = (const float*)d_in[9];
    float* out     = (float*)d_out;
    float* partial = (float*)d_ws;                               // 256 KiB
    ushort* Wp     = (ushort*)((char*)d_ws + WP_BYTE_OFF);       // ~0.75 MiB

    prep_kernel<<<184, 256, 0, stream>>>(W0, W1, W2, Wp);
    ani_mfma_kernel<<<NATOM, 512, 0, stream>>>(aev, species, Wp,
                                               b0, b1, b2, W3, b3, partial);
    reduce_kernel<<<NMOL, 256, 0, stream>>>(partial, out);
}

// Round 11
// 42.951 us; speedup vs baseline: 1.2159x; 1.2159x over previous
//
#include <hip/hip_runtime.h>
#include <hip/hip_bf16.h>

// ANI-1 per-species MLP, v11: TLP-based latency hiding.
// Evidence v8-v10: MfmaUtil*dur ~ 5us of real MFMA work, rest is exposed
// latency; compiler sinks prefetch loads (ILP pipelining unreliable).
// Fix: 4 blocks/CU (32 waves/CU) + global_load_lds X staging:
//  - M=64/block, grid=1024; X staged fp32 HBM->LDS in K=32 dbuf tiles via
//    __builtin_amdgcn_global_load_lds (1KB/wave/tile, 0 VGPR, 0 VALU);
//  - bf16 cvt on consume (2 ds_read_b128 + 4 cvt_pk per fragment);
//  - rule #21 swizzle: XOR-preswizzled GLOBAL source + XOR on LDS READ
//    (chunk ^= row&7) -> 8-bank spread, 2-way (free) vs 16-way linear;
//  - LDS 38KB (XdBuf∪Y1 17.4K + Y0∪Y2 21.5K) -> 4 blocks/CU;
//  - waves_per_eu(8,8): 64-VGPR budget, no staging regs to starve (acc 24).

typedef float f32x4 __attribute__((ext_vector_type(4)));
typedef short s16x8 __attribute__((ext_vector_type(8)));

#define NMOL   128
#define NATOM  512
#define AEV    384
#define MT     64               // molecules per block
#define Y0LD   168
#define Y1LD   136
#define Y2LD   104

// Wp element offsets (bf16 units)
#define PL0    61440            // 160*384
#define PL1    20480            // 128*160
#define PL2    12288            // 96*128
#define BASE0  0
#define BASE1  245760           // 4*PL0
#define BASE2  327680           // BASE1 + 4*PL1
#define WP_BYTE_OFF 262144      // partial buffer (512*128*4) first in d_ws

typedef const __attribute__((address_space(1))) void* gas_ptr;
typedef __attribute__((address_space(3))) void* las_ptr;

__device__ __forceinline__ ushort f2bf(float f) {   // RTN-even
    uint u = __float_as_uint(f);
    return (ushort)((u + 0x7fffu + ((u >> 16) & 1u)) >> 16);
}
__device__ __forceinline__ float bf2f(ushort h) {
    return __uint_as_float(((uint)h) << 16);
}
__device__ __forceinline__ float celu_f(float v) {
    return fmaxf(v, 0.0f) + fminf(0.1f * (__expf(10.0f * v) - 1.0f), 0.0f);
}
__device__ __forceinline__ uint pk2bf(float x, float y) {
    __hip_bfloat162 h2;
    h2.x = __float2bfloat16(x);
    h2.y = __float2bfloat16(y);
    return *(uint*)&h2;
}

// ---- prep: W0..W2 fp32 -> bf16 in MFMA-B-fragment order, 8 elems/thread ----
__global__ __launch_bounds__(256) void prep_kernel(
    const float* __restrict__ W0, const float* __restrict__ W1,
    const float* __restrict__ W2, ushort* __restrict__ Wp)
{
    const int idx = blockIdx.x * 256 + threadIdx.x;   // grid = 47104 (x8 elems)
    int n, k0, KS;
    size_t base;
    const float* src;
    if (idx < 30720) {                        // L0: [4][160][384]
        const int s = idx / 7680, r = idx % 7680;
        n = r / 48; k0 = (r % 48) * 8; KS = 12;
        src = W0 + (size_t)idx * 8;
        base = BASE0 + (size_t)s * PL0;
    } else if (idx < 40960) {                 // L1: [4][128][160]
        const int i2 = idx - 30720;
        const int s = i2 / 2560, r = i2 % 2560;
        n = r / 20; k0 = (r % 20) * 8; KS = 5;
        src = W1 + (size_t)i2 * 8;
        base = BASE1 + (size_t)s * PL1;
    } else {                                  // L2: [4][96][128]
        const int i2 = idx - 40960;
        const int s = i2 / 1536, r = i2 % 1536;
        n = r / 16; k0 = (r % 16) * 8; KS = 4;
        src = W2 + (size_t)i2 * 8;
        base = BASE2 + (size_t)s * PL2;
    }
    const float4 v0 = *(const float4*)(src);
    const float4 v1 = *(const float4*)(src + 4);
    const size_t fo = (size_t)((((n >> 4) * KS + (k0 >> 5)) * 64
                                + ((k0 & 31) >> 3) * 16 + (n & 15)) * 8);
    uint4 w;
    w.x = (uint)f2bf(v0.x) | ((uint)f2bf(v0.y) << 16);
    w.y = (uint)f2bf(v0.z) | ((uint)f2bf(v0.w) << 16);
    w.z = (uint)f2bf(v1.x) | ((uint)f2bf(v1.y) << 16);
    w.w = (uint)f2bf(v1.z) | ((uint)f2bf(v1.w) << 16);
    *(uint4*)(Wp + base + fo) = w;
}

__global__ __attribute__((amdgpu_flat_work_group_size(512, 512),
                          amdgpu_waves_per_eu(8, 8)))
void ani_mfma_kernel(
    const float* __restrict__ aev, const int* __restrict__ species,
    const ushort* __restrict__ Wp,
    const float* __restrict__ b0, const float* __restrict__ b1,
    const float* __restrict__ b2,
    const float* __restrict__ W3, const float* __restrict__ b3,
    float* __restrict__ partial)
{
    // region A: X fp32 dbuf (2 x 8192B) ∪ Y1 bf16 [64][136] (17408B) ∪ red
    // region B: Y0 bf16 [64][168] (21504B) ∪ Y2 bf16 [64][104]
    __shared__ __align__(16) unsigned char smemA[17408];
    __shared__ __align__(16) unsigned char smemB[21504];

    const int bid  = blockIdx.x;
    const int a    = bid >> 1;          // atom
    const int half = bid & 1;           // molecule half
    const int tid  = threadIdx.x;
    const int lane = tid & 63;
    const int wid  = tid >> 6;
    const int mgrp = wid >> 2;          // 0..1 (32-row groups)
    const int ngrp = wid & 3;           // 0..3
    const bool has3 = (ngrp < 2);       // L0 nf=ngrp+8<10; L2 nf=ngrp+4<6

    const int s = species[a];
    const ushort* Bh0 = Wp + BASE0 + (size_t)s * PL0;
    const ushort* Bh1 = Wp + BASE1 + (size_t)s * PL1;
    const ushort* Bh2 = Wp + BASE2 + (size_t)s * PL2;
    const float* b0s = b0 + s * 160;
    const float* b1s = b1 + s * 128;
    const float* b2s = b2 + s * 96;
    const float* w3s = W3 + s * 96;
    const float  bb3 = b3[s];

    ushort* y0buf = (ushort*)smemB;     // [64][168]
    ushort* y1buf = (ushort*)smemA;     // [64][136], alias of X dbuf (X dead)

    // ---- glds source: wave wid stages mols wid*8..+7; lane -> (mol8, k4slot)
    // LDS slot (mol, c16) holds global 16B chunk (c16 ^ (mol&7)) of the tile
    // row (involution; consumer XORs the same way).
    const int mol8 = lane >> 3;         // 0..7
    const int swz  = (lane & 7) ^ mol8; // pre-swizzled global chunk index
    const char* gsrc = (const char*)(aev
        + ((size_t)(half * MT + wid * 8 + mol8) * NATOM + a) * AEV) + swz * 16;
    const int ldsbase = wid * 1024;     // wave's 1KB slice within a buffer

    const f32x4 zero = {0.f, 0.f, 0.f, 0.f};
    f32x4 acc[2][3];
    #pragma unroll
    for (int mf = 0; mf < 2; ++mf)
        #pragma unroll
        for (int ti = 0; ti < 3; ++ti) acc[mf][ti] = zero;

    // ---- L0: 384 -> 160, 12 K-32 tiles, glds double-buffer ----
    {
        const int r0 = mgrp * 32 + (lane & 15);   // fragment row (+ mf*16)
        const int c  = lane >> 4;                 // 0..3, k = c*8..+7

        // prologue: tile 0 -> buf 0
        __builtin_amdgcn_global_load_lds((gas_ptr)(gsrc),
                                         (las_ptr)(smemA + ldsbase), 16, 0, 0);
        __syncthreads();

        #pragma unroll
        for (int t = 0; t < 12; ++t) {
            if (t < 11)   // issue next tile into other buffer; drained at barrier
                __builtin_amdgcn_global_load_lds(
                    (gas_ptr)(gsrc + (t + 1) * 128),
                    (las_ptr)(smemA + (((t + 1) & 1) * 8192) + ldsbase), 16, 0, 0);

            const float* Xb = (const float*)(smemA + (t & 1) * 8192);
            s16x8 ah[2];
            #pragma unroll
            for (int mf = 0; mf < 2; ++mf) {
                const int r = r0 + mf * 16;
                const float* rowp = Xb + r * 32;
                const f32x4 c0 = *(const f32x4*)(rowp + (((2 * c    ) ^ (r & 7)) * 4));
                const f32x4 c1 = *(const f32x4*)(rowp + (((2 * c + 1) ^ (r & 7)) * 4));
                union { s16x8 v; uint u[4]; } rr;
                rr.u[0] = pk2bf(c0.x, c0.y);
                rr.u[1] = pk2bf(c0.z, c0.w);
                rr.u[2] = pk2bf(c1.x, c1.y);
                rr.u[3] = pk2bf(c1.z, c1.w);
                ah[mf] = rr.v;
            }
            #pragma unroll
            for (int ti = 0; ti < 3; ++ti) {
                if (ti < 2 || has3) {
                    const s16x8 bh = *(const s16x8*)(
                        Bh0 + ((size_t)((ngrp + 4 * ti) * 12 + t) * 64 + lane) * 8);
                    acc[0][ti] = __builtin_amdgcn_mfma_f32_16x16x32_bf16(ah[0], bh, acc[0][ti], 0, 0, 0);
                    acc[1][ti] = __builtin_amdgcn_mfma_f32_16x16x32_bf16(ah[1], bh, acc[1][ti], 0, 0, 0);
                }
            }
            if (t < 11) __syncthreads();
        }
    }

    // L1 B preload (flies during L0 epilogue + barrier)
    s16x8 b1r[2][5];
    #pragma unroll
    for (int ks = 0; ks < 5; ++ks) {
        b1r[0][ks] = *(const s16x8*)(Bh1 + ((size_t)((ngrp    ) * 5 + ks) * 64 + lane) * 8);
        b1r[1][ks] = *(const s16x8*)(Bh1 + ((size_t)((ngrp + 4) * 5 + ks) * 64 + lane) * 8);
    }

    // ---- L0 epilogue -> Y0 (regionB, ld 168); X region untouched ----
    #pragma unroll
    for (int ti = 0; ti < 3; ++ti) {
        if (ti < 2 || has3) {
            const int n = (ngrp + 4 * ti) * 16 + (lane & 15);
            const float bv = b0s[n];
            #pragma unroll
            for (int mf = 0; mf < 2; ++mf) {
                #pragma unroll
                for (int r = 0; r < 4; ++r) {
                    const int row = mgrp * 32 + mf * 16 + (lane >> 4) * 4 + r;
                    y0buf[row * Y0LD + n] = f2bf(celu_f(acc[mf][ti][r] + bv));
                }
            }
        }
    }
    __syncthreads();

    // ---- L1: 160 -> 128 (A from Y0, C -> Y1 @ smemA) ----
    f32x4 acc1[2][2];
    #pragma unroll
    for (int mf = 0; mf < 2; ++mf) { acc1[mf][0] = zero; acc1[mf][1] = zero; }
    #pragma unroll
    for (int ks = 0; ks < 5; ++ks) {
        s16x8 ah[2];
        #pragma unroll
        for (int mf = 0; mf < 2; ++mf)
            ah[mf] = *(const s16x8*)(y0buf + (mgrp * 32 + mf * 16 + (lane & 15)) * Y0LD
                                     + ks * 32 + (lane >> 4) * 8);
        #pragma unroll
        for (int mf = 0; mf < 2; ++mf) {
            acc1[mf][0] = __builtin_amdgcn_mfma_f32_16x16x32_bf16(ah[mf], b1r[0][ks], acc1[mf][0], 0, 0, 0);
            acc1[mf][1] = __builtin_amdgcn_mfma_f32_16x16x32_bf16(ah[mf], b1r[1][ks], acc1[mf][1], 0, 0, 0);
        }
    }

    // L2 B preload (completes by the post-L1-epilogue barrier)
    s16x8 b2r[2][4];
    #pragma unroll
    for (int ks = 0; ks < 4; ++ks)
        b2r[0][ks] = *(const s16x8*)(Bh2 + ((size_t)((ngrp) * 4 + ks) * 64 + lane) * 8);
    if (has3) {
        #pragma unroll
        for (int ks = 0; ks < 4; ++ks)
            b2r[1][ks] = *(const s16x8*)(Bh2 + ((size_t)((ngrp + 4) * 4 + ks) * 64 + lane) * 8);
    }

    // ---- L1 epilogue -> Y1 (smemA, ld 136) ----
    #pragma unroll
    for (int t = 0; t < 2; ++t) {
        const int n = (ngrp + 4 * t) * 16 + (lane & 15);
        const float bv = b1s[n];
        #pragma unroll
        for (int mf = 0; mf < 2; ++mf) {
            #pragma unroll
            for (int r = 0; r < 4; ++r) {
                const int row = mgrp * 32 + mf * 16 + (lane >> 4) * 4 + r;
                y1buf[row * Y1LD + n] = f2bf(celu_f(acc1[mf][t][r] + bv));
            }
        }
    }
    __syncthreads();

    // ---- L2: 128 -> 96 (A from Y1, C -> Y2 @ regionB ld 104) ----
    f32x4 acc2[2][2];
    #pragma unroll
    for (int mf = 0; mf < 2; ++mf) { acc2[mf][0] = zero; acc2[mf][1] = zero; }
    #pragma unroll
    for (int ks = 0; ks < 4; ++ks) {
        s16x8 ah[2];
        #pragma unroll
        for (int mf = 0; mf < 2; ++mf)
            ah[mf] = *(const s16x8*)(y1buf + (mgrp * 32 + mf * 16 + (lane & 15)) * Y1LD
                                     + ks * 32 + (lane >> 4) * 8);
        #pragma unroll
        for (int mf = 0; mf < 2; ++mf) {
            acc2[mf][0] = __builtin_amdgcn_mfma_f32_16x16x32_bf16(ah[mf], b2r[0][ks], acc2[mf][0], 0, 0, 0);
            if (has3)
                acc2[mf][1] = __builtin_amdgcn_mfma_f32_16x16x32_bf16(ah[mf], b2r[1][ks], acc2[mf][1], 0, 0, 0);
        }
    }
    __syncthreads();   // Y1 reads done; smemA reused for red below

    // ---- L2 epilogue -> Y2 (regionB, ld 104) ----
    #pragma unroll
    for (int t = 0; t < 2; ++t) {
        if (t == 0 || has3) {
            const int n = (ngrp + 4 * t) * 16 + (lane & 15);   // < 96
            const float bv = b2s[n];
            #pragma unroll
            for (int mf = 0; mf < 2; ++mf) {
                #pragma unroll
                for (int r = 0; r < 4; ++r) {
                    const int row = mgrp * 32 + mf * 16 + (lane >> 4) * 4 + r;
                    y0buf[row * Y2LD + n] = f2bf(celu_f(acc2[mf][t][r] + bv));
                }
            }
        }
    }
    __syncthreads();

    // ---- L3: 96 -> 1 (fp32 vector; red in smemA) ----
    {
        float* red = (float*)smemA;
        const int m = tid & (MT - 1);
        const int q = tid >> 6;       // 0..7, 12 inputs each
        float accv = 0.f;
        #pragma unroll
        for (int ii = 0; ii < 12; ++ii) {
            const int i = q * 12 + ii;
            accv = fmaf(w3s[i], bf2f(y0buf[m * Y2LD + i]), accv);
        }
        red[q * MT + m] = accv;
        __syncthreads();
        if (tid < MT) {
            float sm = bb3;
            #pragma unroll
            for (int qq = 0; qq < 8; ++qq) sm += red[qq * MT + tid];
            partial[(size_t)a * NMOL + half * MT + tid] = sm;
        }
    }
}

__global__ __launch_bounds__(256) void reduce_kernel(
    const float* __restrict__ partial, float* __restrict__ out)
{
    __shared__ float red[256];
    const int m = blockIdx.x;       // molecule
    const int t = threadIdx.x;
    float sv = partial[(size_t)t * NMOL + m] + partial[(size_t)(t + 256) * NMOL + m];
    red[t] = sv;
    __syncthreads();
    #pragma unroll
    for (int w = 128; w > 0; w >>= 1) {
        if (t < w) red[t] += red[t + w];
        __syncthreads();
    }
    if (t == 0) out[m] = red[0];
}

extern "C" void kernel_launch(void* const* d_in, const int* in_sizes, int n_in,
                              void* d_out, int out_size, void* d_ws, size_t ws_size,
                              hipStream_t stream) {
    const float* aev     = (const float*)d_in[0];
    const int*   species = (const int*)  d_in[1];
    const float* W0 = (const float*)d_in[2];
    const float* b0 = (const float*)d_in[3];
    const float* W1 = (const float*)d_in[4];
    const float* b1 = (const float*)d_in[5];
    const float* W2 = (const float*)d_in[6];
    const float* b2 = (const float*)d_in[7];
    const float* W3 = (const float*)d_in[8];
    const float* b3 = (const float*)d_in[9];
    float* out     = (float*)d_out;
    float* partial = (float*)d_ws;                               // 256 KiB
    ushort* Wp     = (ushort*)((char*)d_ws + WP_BYTE_OFF);       // ~0.75 MiB

    prep_kernel<<<184, 256, 0, stream>>>(W0, W1, W2, Wp);
    ani_mfma_kernel<<<NATOM * 2, 512, 0, stream>>>(aev, species, Wp,
                                                   b0, b1, b2, W3, b3, partial);
    reduce_kernel<<<NMOL, 256, 0, stream>>>(partial, out);
}